// Round 2
// baseline (378.409 us; speedup 1.0000x reference)
//
#include <hip/hip_runtime.h>
#include <hip/hip_cooperative_groups.h>

namespace cg = cooperative_groups;

#define BB 64
#define TT 1024
#define CHN 256
#define VV 32000
#define EE 64
#define LL 128
#define NC1 250      // k-chunks for prev_char GEMM (250*128 = 32000)
#define KC1 128
#define TS4 4        // attention t-chunks (256 t each)
#define NV5 500      // logits v-tiles of 64 cols
#define NBLK 256
#define NTHR 512

typedef unsigned short u16;
typedef unsigned int u32;
typedef __attribute__((ext_vector_type(8))) short short8;
typedef __attribute__((ext_vector_type(16))) float f32x16;

__device__ __forceinline__ float fast_rcp(float x) { return __builtin_amdgcn_rcpf(x); }
__device__ __forceinline__ float tanh_fast(float y) {
    float e = __expf(2.0f * y);              // inf/0 limits give +-1 correctly
    return 1.0f - 2.0f * fast_rcp(1.0f + e);
}
__device__ __forceinline__ float sigmoid_fast(float x) {
    return fast_rcp(1.0f + __expf(-x));
}
__device__ __forceinline__ u16 f2bf(float f) {
    u32 u = __float_as_uint(f);
    return (u16)((u + 0x7fffu + ((u >> 16) & 1u)) >> 16);    // RNE
}
__device__ __forceinline__ u32 pack_bf2(float lo, float hi) {
    return (u32)f2bf(lo) | ((u32)f2bf(hi) << 16);
}
__device__ __forceinline__ float bf2f(u16 x) {
    return __uint_as_float(((u32)x) << 16);
}
// Apk index for packed-pair g (k = 2g..2g+1), batch b:
// tile tt = g>>3, kq = (g&7)>>2, reg r = g&3  ->  ((tt*2+kq)*64 + b)*4 + r
__device__ __forceinline__ size_t apk_idx(int g, int b) {
    return ((size_t)(((g >> 3) * 2 + ((g & 7) >> 2)) * 64 + b)) * 4 + (g & 3);
}

// One cooperative kernel, 256 blocks x 512 threads (1 block/CU), 6 phases with
// grid.sync() between: removes 5 inter-kernel launch/drain gaps that dominated
// the 226us measurement (per-kernel BW+VALU floor is only ~50us).
__global__ __launch_bounds__(NTHR, 2) void fused(
    const float* __restrict__ prev_char, const float* __restrict__ Wc,
    const float* __restrict__ pcv, const float* __restrict__ state_h,
    const float* __restrict__ state_c, const float* __restrict__ Wct1,
    const float* __restrict__ lstm_kernel, const float* __restrict__ lstm_rec,
    const float* __restrict__ W_h, const float* __restrict__ F,
    const float* __restrict__ Vattn, const float* __restrict__ Wo,
    const float* __restrict__ Wct2,
    float* __restrict__ outO, float* __restrict__ outCt,
    float* __restrict__ outH, float* __restrict__ outC,
    float* __restrict__ part, float* __restrict__ pS, float* __restrict__ pW,
    float* __restrict__ Htfm, float* __restrict__ psum,
    u32* __restrict__ Apk, u16* __restrict__ expb) {

    __shared__ __align__(16) char smem[65536];
    cg::grid_group grid = cg::this_grid();
    const int blk = blockIdx.x;
    const int t   = threadIdx.x;

    // ---------------- P1: prev_char[64,32000] @ Wc -> part[b][kc][e] ----------------
    if (blk < NC1) {
        float (*sW1)[EE] = (float (*)[EE])smem;            // 32 KB
        float (*sAT)[64] = (float (*)[64])(smem + 32768);  // 32 KB, [k][b]
        const int k0 = blk * KC1;

        #pragma unroll
        for (int f = t; f < 2048; f += NTHR)
            *(float4*)(&sW1[0][0] + f * 4) = *(const float4*)(Wc + (size_t)k0 * EE + f * 4);
        {
            const int bl = t & 63;         // batch row
            const int kq = t >> 6;         // 0..7, 16 cols each
            const float* src = prev_char + (size_t)bl * VV + k0 + kq * 16;
            #pragma unroll
            for (int j4 = 0; j4 < 4; ++j4) {
                float4 v = *(const float4*)(src + j4 * 4);
                sAT[kq * 16 + j4 * 4 + 0][bl] = v.x;
                sAT[kq * 16 + j4 * 4 + 1][bl] = v.y;
                sAT[kq * 16 + j4 * 4 + 2][bl] = v.z;
                sAT[kq * 16 + j4 * 4 + 3][bl] = v.w;
            }
        }
        __syncthreads();

        const int e  = t & 63;
        const int b0 = (t >> 6) * 8;
        float acc[8];
        #pragma unroll
        for (int i = 0; i < 8; ++i) acc[i] = 0.0f;

        #pragma unroll 4
        for (int k = 0; k < KC1; ++k) {
            float wt = sW1[k][e];
            float4 a0 = *(const float4*)&sAT[k][b0];       // wave-uniform -> broadcast
            float4 a1 = *(const float4*)&sAT[k][b0 + 4];
            acc[0] = fmaf(a0.x, wt, acc[0]);
            acc[1] = fmaf(a0.y, wt, acc[1]);
            acc[2] = fmaf(a0.z, wt, acc[2]);
            acc[3] = fmaf(a0.w, wt, acc[3]);
            acc[4] = fmaf(a1.x, wt, acc[4]);
            acc[5] = fmaf(a1.y, wt, acc[5]);
            acc[6] = fmaf(a1.z, wt, acc[6]);
            acc[7] = fmaf(a1.w, wt, acc[7]);
        }
        #pragma unroll
        for (int i = 0; i < 8; ++i)
            part[((size_t)(b0 + i) * NC1 + blk) * EE + e] = acc[i];
    }
    grid.sync();

    // ---------------- P2: reduce part + pcv@Wct1, z-GEMM, gates, Htfm, Apk(h) -------
    if (blk < BB) {
        float (*red)[EE] = (float (*)[EE])smem;            // [8][64]
        float* inp = (float*)(smem + 8 * EE * 4);
        float* sh  = inp + EE;
        float* z   = sh + LL;
        float* nh  = z + 4 * LL;
        const int b = blk;
        const int e = t & 63;
        const int g = t >> 6;          // 0..7

        {
            float s = 0.0f;
            #pragma unroll 4
            for (int j = g; j < NC1; j += 8)               // contiguous 64KB window
                s += part[((size_t)b * NC1 + j) * EE + e];
            const int c0 = g * 32;
            #pragma unroll 8
            for (int c = 0; c < 32; ++c)
                s = fmaf(pcv[b * CHN + c0 + c], Wct1[(size_t)(c0 + c) * EE + e], s);
            red[g][e] = s;
        }
        __syncthreads();
        if (t < EE) {
            float s = 0.0f;
            #pragma unroll
            for (int j = 0; j < 8; ++j) s += red[j][t];
            inp[t] = s;
        } else if (t >= 64 && t < 64 + LL) {
            sh[t - 64] = state_h[b * LL + (t - 64)];
        }
        __syncthreads();
        {
            float a = 0.0f;
            #pragma unroll 8
            for (int e2 = 0; e2 < EE; ++e2) a = fmaf(inp[e2], lstm_kernel[e2 * 512 + t], a);
            #pragma unroll 8
            for (int l = 0; l < LL; ++l) a = fmaf(sh[l], lstm_rec[l * 512 + t], a);
            z[t] = a;
        }
        __syncthreads();
        if (t < LL) {
            float zi = z[t], zf = z[LL + t], zg = z[2 * LL + t], zo = z[3 * LL + t];
            float ig = sigmoid_fast(zi);
            float fg = sigmoid_fast(zf);
            float gg = tanh_fast(zg);
            float og = sigmoid_fast(zo);
            float co = state_c[b * LL + t];
            float cn = fg * co + ig * gg;
            float hn = og * tanh_fast(cn);
            outC[b * LL + t] = fminf(fmaxf(cn, -10.0f), 10.0f);
            outH[b * LL + t] = hn;
            nh[t] = hn;
        }
        __syncthreads();
        if (t < CHN) {
            float a = 0.0f;
            #pragma unroll 8
            for (int l = 0; l < LL; ++l) a = fmaf(nh[l], W_h[l * CHN + t], a);
            Htfm[b * CHN + t] = a;
        } else if (t >= CHN && t < CHN + 64) {
            const int gp = t - CHN;    // packed pairs 0..63 (h part, k=0..127)
            Apk[apk_idx(gp, b)] = pack_bf2(nh[2 * gp], nh[2 * gp + 1]);
        }
    }
    grid.sync();

    // ---------------- P3: attention partials, unit = (b, quarter of T) --------------
    {
        float4* sS4 = (float4*)smem;           // [512]
        float4* sW4 = sS4 + NTHR;              // [512]   (16 KB total)
        const int b    = blk >> 2;
        const int ts   = blk & 3;
        const int lane = t & 63;
        const int w    = t >> 6;               // 0..7 waves, 32 t each
        const int ch   = lane * 4;

        float4 h4 = *(const float4*)(Htfm + b * CHN + ch);
        float4 v4 = *(const float4*)(Vattn + ch);
        float s0 = 0, s1 = 0, s2 = 0, s3 = 0;
        float a0 = 0, a1 = 0, a2 = 0, a3 = 0;

        const float* Fp = F + ((size_t)b * TT + ts * 256 + w * 32) * CHN + ch;
        float4 cur = *(const float4*)(Fp);
        #pragma unroll
        for (int q = 0; q < 32; ++q) {
            float4 nxt;
            if (q < 31) nxt = *(const float4*)(Fp + (size_t)(q + 1) * CHN);
            float e0 = __expf(v4.x * tanh_fast(h4.x + cur.x));
            float e1 = __expf(v4.y * tanh_fast(h4.y + cur.y));
            float e2 = __expf(v4.z * tanh_fast(h4.z + cur.z));
            float e3 = __expf(v4.w * tanh_fast(h4.w + cur.w));
            s0 += e0; s1 += e1; s2 += e2; s3 += e3;
            a0 = fmaf(e0, cur.x, a0); a1 = fmaf(e1, cur.y, a1);
            a2 = fmaf(e2, cur.z, a2); a3 = fmaf(e3, cur.w, a3);
            cur = nxt;
        }
        sS4[t] = make_float4(s0, s1, s2, s3);
        sW4[t] = make_float4(a0, a1, a2, a3);
        __syncthreads();
        if (t < 64) {
            float4 S = sS4[t];
            float4 W4 = sW4[t];
            #pragma unroll
            for (int j = 1; j < 8; ++j) {
                float4 s = sS4[j * 64 + t];
                float4 q = sW4[j * 64 + t];
                S.x += s.x; S.y += s.y; S.z += s.z; S.w += s.w;
                W4.x += q.x; W4.y += q.y; W4.z += q.z; W4.w += q.w;
            }
            int base = (b * TS4 + ts) * CHN + t * 4;
            *(float4*)(pS + base) = S;
            *(float4*)(pW + base) = W4;
        }
    }
    grid.sync();

    // ---------------- P4: reduce TS4 chunks -> c_t + Apk(c) -------------------------
    if (blk < BB) {
        float* sc = (float*)smem;              // [256]
        const int b = blk;
        if (t < CHN) {
            float S = 0.0f, W = 0.0f;
            #pragma unroll
            for (int j = 0; j < TS4; ++j) {
                int idx = (b * TS4 + j) * CHN + t;
                S += pS[idx];
                W += pW[idx];
            }
            float c = W / S;
            outCt[b * CHN + t] = c;
            sc[t] = c;
        }
        __syncthreads();
        if (t < 128)                   // packed pairs 64..191 (c part, k=128..383)
            Apk[apk_idx(64 + t, b)] = pack_bf2(sc[2 * t], sc[2 * t + 1]);
    }
    grid.sync();

    // ---------------- P5: MFMA bf16 logits -> bf16 exp + row partials ---------------
    // Two 64-col v-tiles per block as two 256-thread sub-blocks.
    if (blk < NC1) {
        float (*rp)[4][32] = (float (*)[4][32])smem;       // [2][4][32]
        const int sub  = t >> 8;
        const int tid  = t & 255;
        const int lane = tid & 63;
        const int wv   = tid >> 6;     // 0..3
        const int m    = lane & 31;    // local b (A row / C col)
        const int kq   = lane >> 5;    // k-half select
        const int vt   = blk * 2 + sub;            // 0..499
        const int n0   = vt * 64 + (wv >> 1) * 32;
        const int gb0  = (wv & 1) * 32;

        uint4 af[24];
        #pragma unroll
        for (int tt = 0; tt < 24; ++tt)
            af[tt] = *(const uint4*)&Apk[((size_t)((tt * 2 + kq) * 64) + gb0 + m) * 4];

        f32x16 acc = {0.0f, 0.0f, 0.0f, 0.0f, 0.0f, 0.0f, 0.0f, 0.0f,
                      0.0f, 0.0f, 0.0f, 0.0f, 0.0f, 0.0f, 0.0f, 0.0f};

        float wbuf[3][8];
        #pragma unroll
        for (int pf = 0; pf < 2; ++pf) {   // prefetch tiles 0,1 (rows < 40 -> Wo)
            const float* c0 = Wo + (size_t)(pf * 16 + kq * 8) * VV + n0 + m;
            #pragma unroll
            for (int j = 0; j < 8; ++j) wbuf[pf][j] = c0[(size_t)j * VV];
        }

        #pragma unroll
        for (int tt = 0; tt < 24; ++tt) {
            if (tt < 22) {                 // prefetch tile tt+2
                const int kn = (tt + 2) * 16 + kq * 8;
                const float* cn = (kn < LL ? Wo + (size_t)kn * VV
                                           : Wct2 + (size_t)(kn - LL) * VV) + n0 + m;
                #pragma unroll
                for (int j = 0; j < 8; ++j) wbuf[(tt + 2) % 3][j] = cn[(size_t)j * VV];
            }
            short8 a, b;
            u32 ax = af[tt].x, ay = af[tt].y, az = af[tt].z, aw = af[tt].w;
            #pragma unroll
            for (int r = 0; r < 4; ++r) {
                u32 lo = __float_as_uint(wbuf[tt % 3][2 * r]);
                u32 hi = __float_as_uint(wbuf[tt % 3][2 * r + 1]);
                u32 bp = (lo >> 16) | (hi & 0xffff0000u);   // truncate-to-bf16 pair
                u32 ap = (r == 0) ? ax : (r == 1) ? ay : (r == 2) ? az : aw;
                a[2 * r]     = (short)(ap & 0xffff);
                a[2 * r + 1] = (short)(ap >> 16);
                b[2 * r]     = (short)(bp & 0xffff);
                b[2 * r + 1] = (short)(bp >> 16);
            }
            acc = __builtin_amdgcn_mfma_f32_32x32x16_bf16(a, b, acc, 0, 0, 0);
        }

        // epilogue: exp (f32), bf16 store, row partials. C/D: col=m, row=(r&3)+8(r>>2)+4kq
        float ex[16];
        #pragma unroll
        for (int r = 0; r < 16; ++r) {
            const int row = (r & 3) + 8 * (r >> 2) + 4 * kq;
            ex[r] = __expf(acc[r]);                         // logits bounded ~|4|
            expb[(size_t)(gb0 + row) * VV + n0 + m] = f2bf(ex[r]);
        }
        #pragma unroll
        for (int r = 0; r < 16; ++r) {                      // sum across 32 cols
            float s = ex[r];
            s += __shfl_xor(s, 1, 64);  s += __shfl_xor(s, 2, 64);
            s += __shfl_xor(s, 4, 64);  s += __shfl_xor(s, 8, 64);
            s += __shfl_xor(s, 16, 64);
            ex[r] = s;
        }
        if (m == 0) {                                       // lanes 0 and 32
            #pragma unroll
            for (int r = 0; r < 16; ++r)
                rp[sub][wv][(r & 3) + 8 * (r >> 2) + 4 * kq] = ex[r];
        }
        __syncthreads();
        if (tid < 64) {                // b<32: waves 0+2 ; b>=32: waves 1+3
            const int hb = tid >> 5, r = tid & 31;
            psum[(size_t)vt * BB + tid] = rp[sub][hb][r] + rp[sub][2 + hb][r];
        }
    }
    grid.sync();

    // ---------------- P6: rowsum + normalize bf16 exp -> f32 O ----------------------
    // Two (b, seg-of-4000) units per block as two 256-thread sub-blocks.
    {
        float (*red6)[256] = (float (*)[256])smem;         // [2][256]
        const int sub  = t >> 8;
        const int tid  = t & 255;
        const int unit = blk * 2 + sub;        // 0..511
        const int b    = unit >> 3;
        const int seg  = unit & 7;

        float s = psum[(size_t)tid * BB + b];              // tid < 256 < NV5
        if (tid + 256 < NV5) s += psum[(size_t)(tid + 256) * BB + b];
        red6[sub][tid] = s;
        __syncthreads();
        #pragma unroll
        for (int off = 128; off > 0; off >>= 1) {
            if (tid < off) red6[sub][tid] += red6[sub][tid + off];
            __syncthreads();
        }
        const float inv = fast_rcp(red6[sub][0]);

        const u16* src = expb + (size_t)b * VV + seg * 4000;
        float* dst     = outO + (size_t)b * VV + seg * 4000;
        #pragma unroll 2
        for (int i = tid; i < 1000; i += 256) {            // 1000 x (4 bf16)
            uint2 pk = *(const uint2*)(src + i * 4);
            float4 f;
            f.x = bf2f((u16)(pk.x & 0xffff)) * inv;
            f.y = bf2f((u16)(pk.x >> 16)) * inv;
            f.z = bf2f((u16)(pk.y & 0xffff)) * inv;
            f.w = bf2f((u16)(pk.y >> 16)) * inv;
            *(float4*)(dst + i * 4) = f;
        }
    }
}

extern "C" void kernel_launch(void* const* d_in, const int* in_sizes, int n_in,
                              void* d_out, int out_size, void* d_ws, size_t ws_size,
                              hipStream_t stream) {
    (void)in_sizes; (void)n_in; (void)out_size; (void)ws_size;
    const float* pcv       = (const float*)d_in[0];
    const float* F         = (const float*)d_in[1];
    const float* prev_char = (const float*)d_in[2];
    const float* state_h   = (const float*)d_in[3];
    const float* state_c   = (const float*)d_in[4];
    const float* Wc        = (const float*)d_in[5];
    const float* Wct1      = (const float*)d_in[6];
    const float* Wo        = (const float*)d_in[7];
    const float* Wct2      = (const float*)d_in[8];
    const float* lstm_k    = (const float*)d_in[9];
    const float* lstm_r    = (const float*)d_in[10];
    const float* W_h       = (const float*)d_in[11];
    const float* Vattn     = (const float*)d_in[12];

    // outputs: float32, concatenated flat in return order
    float* outO  = (float*)d_out;                  // [64][32000]
    float* outCt = outO + (size_t)BB * VV;         // [64][256]
    float* outH  = outCt + (size_t)BB * CHN;       // [64][128]
    float* outC  = outH + (size_t)BB * LL;         // [64][128]

    float* ws     = (float*)d_ws;
    float* part   = ws;                            // 250*64*64 = 1,024,000 f
    float* pS     = part + (size_t)NC1 * BB * EE;  // 64*4*256 = 65,536 f
    float* pW     = pS + (size_t)BB * TS4 * CHN;   // 65,536 f
    float* Htfm   = pW + (size_t)BB * TS4 * CHN;   // 16,384 f
    float* psum   = Htfm + (size_t)BB * CHN;       // 500*64 = 32,000 f
    u32*   Apk    = (u32*)(psum + (size_t)NV5 * BB);   // 24*2*64*4 = 12,288 u32
    u16*   expb   = (u16*)(Apk + 12288);           // 64*32000 u16 = 4.1 MB

    void* args[] = {
        (void*)&prev_char, (void*)&Wc, (void*)&pcv, (void*)&state_h, (void*)&state_c,
        (void*)&Wct1, (void*)&lstm_k, (void*)&lstm_r, (void*)&W_h, (void*)&F,
        (void*)&Vattn, (void*)&Wo, (void*)&Wct2,
        (void*)&outO, (void*)&outCt, (void*)&outH, (void*)&outC,
        (void*)&part, (void*)&pS, (void*)&pW, (void*)&Htfm, (void*)&psum,
        (void*)&Apk, (void*)&expb
    };
    hipLaunchCooperativeKernel((const void*)fused, dim3(NBLK), dim3(NTHR),
                               args, 0, stream);
}

// Round 3
// 322.622 us; speedup vs baseline: 1.1729x; 1.1729x over previous
//
#include <hip/hip_runtime.h>
#include <hip/hip_bf16.h>

#define BB 64
#define TT 1024
#define CHN 256
#define VV 32000
#define EE 64
#define LL 128
#define NC1 250      // k1 k-chunks (250*128 = 32000)
#define KC1 128
#define TS 16        // attention t-chunks (64 t each)

typedef unsigned short u16;
typedef unsigned int u32;
typedef __attribute__((ext_vector_type(8))) short short8;
typedef __attribute__((ext_vector_type(16))) float f32x16;

__device__ __forceinline__ float fast_rcp(float x) { return __builtin_amdgcn_rcpf(x); }
__device__ __forceinline__ float tanh_fast(float y) {
    float e = __expf(2.0f * y);              // inf/0 limits give +-1 correctly
    return 1.0f - 2.0f * fast_rcp(1.0f + e);
}
__device__ __forceinline__ float sigmoid_fast(float x) {
    return fast_rcp(1.0f + __expf(-x));
}
__device__ __forceinline__ u16 f2bf(float f) {
    u32 u = __float_as_uint(f);
    return (u16)((u + 0x7fffu + ((u >> 16) & 1u)) >> 16);    // RNE
}
__device__ __forceinline__ u32 pack_bf2(float lo, float hi) {
    return (u32)f2bf(lo) | ((u32)f2bf(hi) << 16);
}
__device__ __forceinline__ float bf2f(u16 x) {
    return __uint_as_float(((u32)x) << 16);
}
// Apk index for packed-pair g (k = 2g..2g+1), batch b:
// tile tt = g>>3, kq = (g&7)>>2, reg r = g&3  ->  ((tt*2+kq)*64 + b)*4 + r
__device__ __forceinline__ size_t apk_idx(int g, int b) {
    return ((size_t)(((g >> 3) * 2 + ((g & 7) >> 2)) * 64 + b)) * 4 + (g & 3);
}

// ---------------- K1: prev_char[64,32000] @ Wc[32000,64] -> part[b][kc][e] -----------
__global__ __launch_bounds__(256) void k1_stage1(const float* __restrict__ A,
                                                 const float* __restrict__ Wc,
                                                 float* __restrict__ part) {
    __shared__ float sW[KC1][EE];      // 32 KB
    __shared__ float sAT[KC1][32];     // 16 KB, transposed: [k][local_b]
    const int kc = blockIdx.x;
    const int k0 = kc * KC1;
    const int y  = blockIdx.y;
    const int t  = threadIdx.x;

    #pragma unroll
    for (int f = t; f < 2048; f += 256)
        *(float4*)(&sW[0][0] + f * 4) = *(const float4*)(Wc + (size_t)k0 * EE + f * 4);
    {
        const int bl = t & 31;
        const int kq = t >> 5;         // 0..7
        const float* src = A + (size_t)(y * 32 + bl) * VV + k0 + kq * 16;
        #pragma unroll
        for (int j4 = 0; j4 < 4; ++j4) {
            float4 v = *(const float4*)(src + j4 * 4);
            sAT[kq * 16 + j4 * 4 + 0][bl] = v.x;
            sAT[kq * 16 + j4 * 4 + 1][bl] = v.y;
            sAT[kq * 16 + j4 * 4 + 2][bl] = v.z;
            sAT[kq * 16 + j4 * 4 + 3][bl] = v.w;
        }
    }
    __syncthreads();

    const int e  = t & 63;
    const int b0 = (t >> 6) * 8;
    float acc[8];
    #pragma unroll
    for (int i = 0; i < 8; ++i) acc[i] = 0.0f;

    #pragma unroll 4
    for (int k = 0; k < KC1; ++k) {
        float wt = sW[k][e];
        float4 a0 = *(const float4*)&sAT[k][b0];           // uniform -> broadcast
        float4 a1 = *(const float4*)&sAT[k][b0 + 4];
        acc[0] = fmaf(a0.x, wt, acc[0]);
        acc[1] = fmaf(a0.y, wt, acc[1]);
        acc[2] = fmaf(a0.z, wt, acc[2]);
        acc[3] = fmaf(a0.w, wt, acc[3]);
        acc[4] = fmaf(a1.x, wt, acc[4]);
        acc[5] = fmaf(a1.y, wt, acc[5]);
        acc[6] = fmaf(a1.z, wt, acc[6]);
        acc[7] = fmaf(a1.w, wt, acc[7]);
    }
    const int gb = y * 32 + b0;
    #pragma unroll
    for (int i = 0; i < 8; ++i)
        part[((size_t)(gb + i) * NC1 + kc) * EE + e] = acc[i];
}

// ---------------- K2: reduce part + pcv@Wct1, z-GEMM, gates, H_tfm, Apk(h) -----------
// Also zeroes the K3 accumulators (accS/accW/cnt) for this batch (poisoned each iter).
__global__ __launch_bounds__(512) void k2_lstm(const float* __restrict__ part,
    const float* __restrict__ pcv, const float* __restrict__ state_h,
    const float* __restrict__ state_c, const float* __restrict__ Wct1,
    const float* __restrict__ lstm_kernel, const float* __restrict__ lstm_rec,
    const float* __restrict__ W_h,
    float* __restrict__ out_newh, float* __restrict__ out_newc,
    u32* __restrict__ Apk, float* __restrict__ Htfm,
    float* __restrict__ accS, float* __restrict__ accW, u32* __restrict__ cnt) {
    __shared__ float red[8][EE];
    __shared__ float inp[EE];
    __shared__ float sh[LL];
    __shared__ float z[4 * LL];
    __shared__ float nh[LL];
    const int b = blockIdx.x;
    const int t = threadIdx.x;
    const int e  = t & 63;
    const int g  = t >> 6;          // 0..7

    // zero K3 accumulators for this batch (stream order guarantees done before K3)
    if (t < CHN) {
        accS[b * CHN + t] = 0.0f;
        accW[b * CHN + t] = 0.0f;
    }
    if (t == 511) cnt[b] = 0u;

    {
        float s = 0.0f;
        #pragma unroll 4
        for (int j = g; j < NC1; j += 8)                       // contiguous 64KB window
            s += part[((size_t)b * NC1 + j) * EE + e];
        const int c0 = g * 32;
        #pragma unroll 8
        for (int c = 0; c < 32; ++c)
            s = fmaf(pcv[b * CHN + c0 + c], Wct1[(size_t)(c0 + c) * EE + e], s);
        red[g][e] = s;
    }
    __syncthreads();
    if (t < EE) {
        float s = 0.0f;
        #pragma unroll
        for (int j = 0; j < 8; ++j) s += red[j][t];
        inp[t] = s;
    } else if (t >= 64 && t < 64 + LL) {
        sh[t - 64] = state_h[b * LL + (t - 64)];
    }
    __syncthreads();
    {
        float a = 0.0f;
        #pragma unroll 8
        for (int e2 = 0; e2 < EE; ++e2) a = fmaf(inp[e2], lstm_kernel[e2 * 512 + t], a);
        #pragma unroll 8
        for (int l = 0; l < LL; ++l) a = fmaf(sh[l], lstm_rec[l * 512 + t], a);
        z[t] = a;
    }
    __syncthreads();
    if (t < LL) {
        float zi = z[t], zf = z[LL + t], zg = z[2 * LL + t], zo = z[3 * LL + t];
        float ig = sigmoid_fast(zi);
        float fg = sigmoid_fast(zf);
        float gg = tanh_fast(zg);
        float og = sigmoid_fast(zo);
        float co = state_c[b * LL + t];
        float cn = fg * co + ig * gg;
        float hn = og * tanh_fast(cn);
        out_newc[b * LL + t] = fminf(fmaxf(cn, -10.0f), 10.0f);
        out_newh[b * LL + t] = hn;
        nh[t] = hn;
    }
    __syncthreads();
    if (t < CHN) {
        float a = 0.0f;
        #pragma unroll 8
        for (int l = 0; l < LL; ++l) a = fmaf(nh[l], W_h[l * CHN + t], a);
        Htfm[b * CHN + t] = a;
    } else if (t >= CHN && t < CHN + 64) {
        const int gp = t - CHN;        // packed pairs 0..63 (h part, k=0..127)
        Apk[apk_idx(gp, b)] = pack_bf2(nh[2 * gp], nh[2 * gp + 1]);
    }
}

// ---------------- K3: attention partials + fused combine (last block per batch) ------
// 4-deep batched loads on the 64MB F stream (was 1-deep prefetch): 4x MLP.
// Each block atomicAdds its 256-ch partial S/W; the 16th finisher block for batch b
// computes c_t = W/S, writes outCt and Apk(c). Replaces the old K4 kernel.
__global__ __launch_bounds__(256) void k3_attn(const float* __restrict__ F,
    const float* __restrict__ Htfm, const float* __restrict__ Vattn,
    float* __restrict__ accS, float* __restrict__ accW, u32* __restrict__ cnt,
    float* __restrict__ out_ct, u32* __restrict__ Apk) {
    __shared__ float4 sS[256];
    __shared__ float4 sW[256];
    __shared__ int lastFlag;
    const int b    = blockIdx.x;
    const int ts   = blockIdx.y;
    const int tid  = threadIdx.x;
    const int lane = tid & 63;
    const int w    = tid >> 6;
    const int ch   = lane * 4;

    float4 h = *(const float4*)(Htfm + b * CHN + ch);
    float4 v = *(const float4*)(Vattn + ch);
    float s0 = 0, s1 = 0, s2 = 0, s3 = 0;
    float a0 = 0, a1 = 0, a2 = 0, a3 = 0;

    const float* Fp = F + ((size_t)b * TT + ts * 64 + w * 16) * CHN + ch;
    #pragma unroll
    for (int q = 0; q < 16; q += 4) {
        float4 c0 = *(const float4*)(Fp + (size_t)(q + 0) * CHN);
        float4 c1 = *(const float4*)(Fp + (size_t)(q + 1) * CHN);
        float4 c2 = *(const float4*)(Fp + (size_t)(q + 2) * CHN);
        float4 c3 = *(const float4*)(Fp + (size_t)(q + 3) * CHN);
        #pragma unroll
        for (int j = 0; j < 4; ++j) {
            float4 cu = (j == 0) ? c0 : (j == 1) ? c1 : (j == 2) ? c2 : c3;
            float e0 = __expf(v.x * tanh_fast(h.x + cu.x));
            float e1 = __expf(v.y * tanh_fast(h.y + cu.y));
            float e2 = __expf(v.z * tanh_fast(h.z + cu.z));
            float e3 = __expf(v.w * tanh_fast(h.w + cu.w));
            s0 += e0; s1 += e1; s2 += e2; s3 += e3;
            a0 = fmaf(e0, cu.x, a0); a1 = fmaf(e1, cu.y, a1);
            a2 = fmaf(e2, cu.z, a2); a3 = fmaf(e3, cu.w, a3);
        }
    }
    sS[tid] = make_float4(s0, s1, s2, s3);
    sW[tid] = make_float4(a0, a1, a2, a3);
    __syncthreads();
    if (tid < 64) {
        float4 S = sS[tid];
        float4 W = sW[tid];
        #pragma unroll
        for (int j = 1; j < 4; ++j) {
            float4 s = sS[j * 64 + tid];
            float4 q = sW[j * 64 + tid];
            S.x += s.x; S.y += s.y; S.z += s.z; S.w += s.w;
            W.x += q.x; W.y += q.y; W.z += q.z; W.w += q.w;
        }
        const int base = b * CHN + tid * 4;
        atomicAdd(&accS[base + 0], S.x);
        atomicAdd(&accS[base + 1], S.y);
        atomicAdd(&accS[base + 2], S.z);
        atomicAdd(&accS[base + 3], S.w);
        atomicAdd(&accW[base + 0], W.x);
        atomicAdd(&accW[base + 1], W.y);
        atomicAdd(&accW[base + 2], W.z);
        atomicAdd(&accW[base + 3], W.w);
    }
    __threadfence();                   // make this block's atomics device-visible
    __syncthreads();
    if (tid == 0) {
        u32 old = atomicAdd(&cnt[b], 1u);
        lastFlag = (old == TS - 1) ? 1 : 0;
    }
    __syncthreads();
    if (lastFlag) {                    // finisher: all 16 chunks for batch b done
        float* sc = (float*)sS;        // reuse LDS
        float S = atomicAdd(&accS[b * CHN + tid], 0.0f);   // coherent read
        float W = atomicAdd(&accW[b * CHN + tid], 0.0f);
        float c = W / S;
        out_ct[b * CHN + tid] = c;
        sc[tid] = c;
        __syncthreads();
        if (tid < 128)                 // packed pairs 64..191 (c part, k=128..383)
            Apk[apk_idx(64 + tid, b)] = pack_bf2(sc[2 * tid], sc[2 * tid + 1]);
    }
}

// ---------------- K5: MFMA bf16 logits -> bf16 exp + per-block row partials ----------
// grid (250 v-tiles of 128, 2 b-halves) x 256 thr. Wave computes 32b x 32v, K=384
// via 24 x mfma_f32_32x32x16_bf16. W streamed f32 -> truncated bf16, 2-tile-deep
// prefetch (16 loads in flight, was 8).
__global__ __launch_bounds__(256) void k5_logits(const float* __restrict__ Wo,
    const float* __restrict__ Wct2, const u32* __restrict__ Apk,
    u16* __restrict__ expb, float* __restrict__ psum) {
    __shared__ float rp[4][32];
    const int t    = threadIdx.x;
    const int lane = t & 63;
    const int wv   = t >> 6;
    const int m    = lane & 31;        // local b (A row / C col)
    const int kq   = lane >> 5;        // k-half select
    const int y    = blockIdx.y;
    const int n0   = blockIdx.x * 128 + wv * 32;
    const int gb0  = y * 32;

    uint4 af[24];
    #pragma unroll
    for (int tt = 0; tt < 24; ++tt)
        af[tt] = *(const uint4*)&Apk[((size_t)((tt * 2 + kq) * 64) + gb0 + m) * 4];

    f32x16 acc = {0.0f, 0.0f, 0.0f, 0.0f, 0.0f, 0.0f, 0.0f, 0.0f,
                  0.0f, 0.0f, 0.0f, 0.0f, 0.0f, 0.0f, 0.0f, 0.0f};

    float wbuf[3][8];
    #pragma unroll
    for (int pf = 0; pf < 2; ++pf) {   // prefetch tiles 0,1 (rows < 40 -> always Wo)
        const float* c0 = Wo + (size_t)(pf * 16 + kq * 8) * VV + n0 + m;
        #pragma unroll
        for (int j = 0; j < 8; ++j) wbuf[pf][j] = c0[(size_t)j * VV];
    }

    #pragma unroll
    for (int tt = 0; tt < 24; ++tt) {
        if (tt < 22) {                 // prefetch tile tt+2
            const int kn = (tt + 2) * 16 + kq * 8;
            const float* cn = (kn < LL ? Wo + (size_t)kn * VV
                                       : Wct2 + (size_t)(kn - LL) * VV) + n0 + m;
            #pragma unroll
            for (int j = 0; j < 8; ++j) wbuf[(tt + 2) % 3][j] = cn[(size_t)j * VV];
        }
        short8 a, b;
        u32 ax = af[tt].x, ay = af[tt].y, az = af[tt].z, aw = af[tt].w;
        #pragma unroll
        for (int r = 0; r < 4; ++r) {
            u32 lo = __float_as_uint(wbuf[tt % 3][2 * r]);
            u32 hi = __float_as_uint(wbuf[tt % 3][2 * r + 1]);
            u32 bp = (lo >> 16) | (hi & 0xffff0000u);       // truncate-to-bf16 pair
            u32 ap = (r == 0) ? ax : (r == 1) ? ay : (r == 2) ? az : aw;
            a[2 * r]     = (short)(ap & 0xffff);
            a[2 * r + 1] = (short)(ap >> 16);
            b[2 * r]     = (short)(bp & 0xffff);
            b[2 * r + 1] = (short)(bp >> 16);
        }
        acc = __builtin_amdgcn_mfma_f32_32x32x16_bf16(a, b, acc, 0, 0, 0);
    }

    // epilogue: exp (f32), bf16 store, row partials. C/D: col=m, row=(r&3)+8(r>>2)+4kq
    float ex[16];
    #pragma unroll
    for (int r = 0; r < 16; ++r) {
        const int row = (r & 3) + 8 * (r >> 2) + 4 * kq;
        ex[r] = __expf(acc[r]);                             // logits bounded ~|4|
        expb[(size_t)(gb0 + row) * VV + n0 + m] = f2bf(ex[r]);
    }
    #pragma unroll
    for (int r = 0; r < 16; ++r) {                          // sum across 32 cols
        float s = ex[r];
        s += __shfl_xor(s, 1, 64);  s += __shfl_xor(s, 2, 64);
        s += __shfl_xor(s, 4, 64);  s += __shfl_xor(s, 8, 64);
        s += __shfl_xor(s, 16, 64);
        ex[r] = s;
    }
    if (m == 0) {                                           // lanes 0 and 32
        #pragma unroll
        for (int r = 0; r < 16; ++r)
            rp[wv][(r & 3) + 8 * (r >> 2) + 4 * kq] = ex[r];
    }
    __syncthreads();
    if (t < 32)
        psum[(size_t)blockIdx.x * BB + gb0 + t] =
            rp[0][t] + rp[1][t] + rp[2][t] + rp[3][t];
}

// ---------------- K5c: rowsum (in-block) + normalize bf16 exp -> f32 O ---------------
// grid (64 rows, 4 segs of 8000 v) x 256 thr.
__global__ __launch_bounds__(256) void k5c_norm(const u16* __restrict__ expb,
    const float* __restrict__ psum, float* __restrict__ O) {
    __shared__ float red[256];
    const int b   = blockIdx.x;
    const int seg = blockIdx.y;
    const int t   = threadIdx.x;

    red[t] = (t < NC1) ? psum[(size_t)t * BB + b] : 0.0f;
    __syncthreads();
    #pragma unroll
    for (int off = 128; off > 0; off >>= 1) {
        if (t < off) red[t] += red[t + off];
        __syncthreads();
    }
    const float inv = fast_rcp(red[0]);

    const u16* src = expb + (size_t)b * VV + seg * 8000;
    float* dst     = O + (size_t)b * VV + seg * 8000;
    #pragma unroll 2
    for (int i = t; i < 2000; i += 256) {            // 2000 x (4 bf16)
        uint2 pk = *(const uint2*)(src + i * 4);
        float4 f;
        f.x = bf2f((u16)(pk.x & 0xffff)) * inv;
        f.y = bf2f((u16)(pk.x >> 16)) * inv;
        f.z = bf2f((u16)(pk.y & 0xffff)) * inv;
        f.w = bf2f((u16)(pk.y >> 16)) * inv;
        *(float4*)(dst + i * 4) = f;
    }
}

extern "C" void kernel_launch(void* const* d_in, const int* in_sizes, int n_in,
                              void* d_out, int out_size, void* d_ws, size_t ws_size,
                              hipStream_t stream) {
    (void)in_sizes; (void)n_in; (void)out_size; (void)ws_size;
    const float* pcv       = (const float*)d_in[0];
    const float* F         = (const float*)d_in[1];
    const float* prev_char = (const float*)d_in[2];
    const float* state_h   = (const float*)d_in[3];
    const float* state_c   = (const float*)d_in[4];
    const float* Wc        = (const float*)d_in[5];
    const float* Wct1      = (const float*)d_in[6];
    const float* Wo        = (const float*)d_in[7];
    const float* Wct2      = (const float*)d_in[8];
    const float* lstm_k    = (const float*)d_in[9];
    const float* lstm_r    = (const float*)d_in[10];
    const float* W_h       = (const float*)d_in[11];
    const float* Vattn     = (const float*)d_in[12];

    // outputs: float32, concatenated flat in return order
    float* outO  = (float*)d_out;                  // [64][32000]
    float* outCt = outO + (size_t)BB * VV;         // [64][256]
    float* outH  = outCt + (size_t)BB * CHN;       // [64][128]
    float* outC  = outH + (size_t)BB * LL;         // [64][128]

    float* ws     = (float*)d_ws;
    float* part   = ws;                            // 250*64*64 = 1,024,000 f
    float* accS   = part + (size_t)NC1 * BB * EE;  // 64*256 = 16,384 f
    float* accW   = accS + (size_t)BB * CHN;       // 16,384 f
    float* Htfm   = accW + (size_t)BB * CHN;       // 16,384 f
    float* psum   = Htfm + (size_t)BB * CHN;       // 250*64 = 16,000 f
    u32*   cnt    = (u32*)(psum + (size_t)NC1 * BB);   // 64 u32
    u32*   Apk    = (u32*)(cnt + 64);              // 24*2*64*4 = 12,288 u32
    u16*   expb   = (u16*)(Apk + 12288);           // 64*32000 u16 = 4.1 MB

    hipLaunchKernelGGL(k1_stage1, dim3(NC1, 2), dim3(256), 0, stream, prev_char, Wc, part);
    hipLaunchKernelGGL(k2_lstm, dim3(BB), dim3(512), 0, stream, part, pcv, state_h,
                       state_c, Wct1, lstm_k, lstm_r, W_h, outH, outC, Apk, Htfm,
                       accS, accW, cnt);
    hipLaunchKernelGGL(k3_attn, dim3(BB, TS), dim3(256), 0, stream, F, Htfm, Vattn,
                       accS, accW, cnt, outCt, Apk);
    hipLaunchKernelGGL(k5_logits, dim3(NC1, 2), dim3(256), 0, stream, Wo, Wct2, Apk, expb, psum);
    hipLaunchKernelGGL(k5c_norm, dim3(BB, 4), dim3(256), 0, stream, expb, psum, outO);
}

// Round 6
// 222.922 us; speedup vs baseline: 1.6975x; 1.4472x over previous
//
#include <hip/hip_runtime.h>
#include <hip/hip_bf16.h>

#define BB 64
#define TT 1024
#define CHN 256
#define VV 32000
#define EE 64
#define LL 128
#define NC1 250      // k1 k-chunks (250*128 = 32000)
#define KC1 128
#define TS 16        // attention t-chunks (64 t each)

typedef unsigned short u16;
typedef unsigned int u32;
typedef __attribute__((ext_vector_type(8))) short short8;
typedef __attribute__((ext_vector_type(16))) float f32x16;

__device__ __forceinline__ float fast_rcp(float x) { return __builtin_amdgcn_rcpf(x); }
__device__ __forceinline__ float tanh_fast(float y) {
    float e = __expf(2.0f * y);              // inf/0 limits give +-1 correctly
    return 1.0f - 2.0f * fast_rcp(1.0f + e);
}
__device__ __forceinline__ float sigmoid_fast(float x) {
    return fast_rcp(1.0f + __expf(-x));
}
__device__ __forceinline__ u16 f2bf(float f) {
    u32 u = __float_as_uint(f);
    return (u16)((u + 0x7fffu + ((u >> 16) & 1u)) >> 16);    // RNE
}
__device__ __forceinline__ u32 pack_bf2(float lo, float hi) {
    return (u32)f2bf(lo) | ((u32)f2bf(hi) << 16);
}
__device__ __forceinline__ float bf2f(u16 x) {
    return __uint_as_float(((u32)x) << 16);
}
// Apk index for packed-pair g (k = 2g..2g+1), batch b:
// tile tt = g>>3, kq = (g&7)>>2, reg r = g&3  ->  ((tt*2+kq)*64 + b)*4 + r
__device__ __forceinline__ size_t apk_idx(int g, int b) {
    return ((size_t)(((g >> 3) * 2 + ((g & 7) >> 2)) * 64 + b)) * 4 + (g & 3);
}

// ---------------- K1: prev_char[64,32000] @ Wc[32000,64] -> part[b][kc][e] -----------
__global__ __launch_bounds__(256) void k1_stage1(const float* __restrict__ A,
                                                 const float* __restrict__ Wc,
                                                 float* __restrict__ part) {
    __shared__ float sW[KC1][EE];      // 32 KB
    __shared__ float sAT[KC1][32];     // 16 KB, transposed: [k][local_b]
    const int kc = blockIdx.x;
    const int k0 = kc * KC1;
    const int y  = blockIdx.y;
    const int t  = threadIdx.x;

    #pragma unroll
    for (int f = t; f < 2048; f += 256)
        *(float4*)(&sW[0][0] + f * 4) = *(const float4*)(Wc + (size_t)k0 * EE + f * 4);
    {
        const int bl = t & 31;
        const int kq = t >> 5;         // 0..7
        const float* src = A + (size_t)(y * 32 + bl) * VV + k0 + kq * 16;
        #pragma unroll
        for (int j4 = 0; j4 < 4; ++j4) {
            float4 v = *(const float4*)(src + j4 * 4);
            sAT[kq * 16 + j4 * 4 + 0][bl] = v.x;
            sAT[kq * 16 + j4 * 4 + 1][bl] = v.y;
            sAT[kq * 16 + j4 * 4 + 2][bl] = v.z;
            sAT[kq * 16 + j4 * 4 + 3][bl] = v.w;
        }
    }
    __syncthreads();

    const int e  = t & 63;
    const int b0 = (t >> 6) * 8;
    float acc[8];
    #pragma unroll
    for (int i = 0; i < 8; ++i) acc[i] = 0.0f;

    #pragma unroll 4
    for (int k = 0; k < KC1; ++k) {
        float wt = sW[k][e];
        float4 a0 = *(const float4*)&sAT[k][b0];           // uniform -> broadcast
        float4 a1 = *(const float4*)&sAT[k][b0 + 4];
        acc[0] = fmaf(a0.x, wt, acc[0]);
        acc[1] = fmaf(a0.y, wt, acc[1]);
        acc[2] = fmaf(a0.z, wt, acc[2]);
        acc[3] = fmaf(a0.w, wt, acc[3]);
        acc[4] = fmaf(a1.x, wt, acc[4]);
        acc[5] = fmaf(a1.y, wt, acc[5]);
        acc[6] = fmaf(a1.z, wt, acc[6]);
        acc[7] = fmaf(a1.w, wt, acc[7]);
    }
    const int gb = y * 32 + b0;
    #pragma unroll
    for (int i = 0; i < 8; ++i)
        part[((size_t)(gb + i) * NC1 + kc) * EE + e] = acc[i];
}

// ---------------- K2: reduce part + pcv@Wct1, z-GEMM, gates, H_tfm, Apk(h) -----------
__global__ __launch_bounds__(512) void k2_lstm(const float* __restrict__ part,
    const float* __restrict__ pcv, const float* __restrict__ state_h,
    const float* __restrict__ state_c, const float* __restrict__ Wct1,
    const float* __restrict__ lstm_kernel, const float* __restrict__ lstm_rec,
    const float* __restrict__ W_h,
    float* __restrict__ out_newh, float* __restrict__ out_newc,
    u32* __restrict__ Apk, float* __restrict__ Htfm) {
    __shared__ float red[8][EE];
    __shared__ float inp[EE];
    __shared__ float sh[LL];
    __shared__ float z[4 * LL];
    __shared__ float nh[LL];
    const int b = blockIdx.x;
    const int t = threadIdx.x;
    const int e  = t & 63;
    const int g  = t >> 6;          // 0..7

    {
        float s = 0.0f;
        #pragma unroll 4
        for (int j = g; j < NC1; j += 8)                       // contiguous 64KB window
            s += part[((size_t)b * NC1 + j) * EE + e];
        const int c0 = g * 32;
        #pragma unroll 8
        for (int c = 0; c < 32; ++c)
            s = fmaf(pcv[b * CHN + c0 + c], Wct1[(size_t)(c0 + c) * EE + e], s);
        red[g][e] = s;
    }
    __syncthreads();
    if (t < EE) {
        float s = 0.0f;
        #pragma unroll
        for (int j = 0; j < 8; ++j) s += red[j][t];
        inp[t] = s;
    } else if (t >= 64 && t < 64 + LL) {
        sh[t - 64] = state_h[b * LL + (t - 64)];
    }
    __syncthreads();
    {
        float a = 0.0f;
        #pragma unroll 8
        for (int e2 = 0; e2 < EE; ++e2) a = fmaf(inp[e2], lstm_kernel[e2 * 512 + t], a);
        #pragma unroll 8
        for (int l = 0; l < LL; ++l) a = fmaf(sh[l], lstm_rec[l * 512 + t], a);
        z[t] = a;
    }
    __syncthreads();
    if (t < LL) {
        float zi = z[t], zf = z[LL + t], zg = z[2 * LL + t], zo = z[3 * LL + t];
        float ig = sigmoid_fast(zi);
        float fg = sigmoid_fast(zf);
        float gg = tanh_fast(zg);
        float og = sigmoid_fast(zo);
        float co = state_c[b * LL + t];
        float cn = fg * co + ig * gg;
        float hn = og * tanh_fast(cn);
        out_newc[b * LL + t] = fminf(fmaxf(cn, -10.0f), 10.0f);
        out_newh[b * LL + t] = hn;
        nh[t] = hn;
    }
    __syncthreads();
    if (t < CHN) {
        float a = 0.0f;
        #pragma unroll 8
        for (int l = 0; l < LL; ++l) a = fmaf(nh[l], W_h[l * CHN + t], a);
        Htfm[b * CHN + t] = a;
    } else if (t >= CHN && t < CHN + 64) {
        const int gp = t - CHN;        // packed pairs 0..63 (h part, k=0..127)
        Apk[apk_idx(gp, b)] = pack_bf2(nh[2 * gp], nh[2 * gp + 1]);
    }
}

// ---------------- K3: attention partials per (b, ts) ---------------------------------
// 4-deep batched loads (4 outstanding float4/wave) on the 64MB F stream; no atomics,
// no fences — partials to pS/pW, combined by K4 (kernel boundary = the cheap sync).
__global__ __launch_bounds__(256) void k3_attn(const float* __restrict__ F,
    const float* __restrict__ Htfm, const float* __restrict__ Vattn,
    float* __restrict__ pS, float* __restrict__ pW) {
    __shared__ float4 sS[256];
    __shared__ float4 sW[256];
    const int b    = blockIdx.x;
    const int ts   = blockIdx.y;
    const int lane = threadIdx.x & 63;
    const int w    = threadIdx.x >> 6;
    const int ch   = lane * 4;

    float4 h = *(const float4*)(Htfm + b * CHN + ch);
    float4 v = *(const float4*)(Vattn + ch);
    float s0 = 0, s1 = 0, s2 = 0, s3 = 0;
    float a0 = 0, a1 = 0, a2 = 0, a3 = 0;

    const float* Fp = F + ((size_t)b * TT + ts * (TT / TS) + w * 16) * CHN + ch;
    #pragma unroll
    for (int q = 0; q < 16; q += 4) {
        float4 c0 = *(const float4*)(Fp + (size_t)(q + 0) * CHN);
        float4 c1 = *(const float4*)(Fp + (size_t)(q + 1) * CHN);
        float4 c2 = *(const float4*)(Fp + (size_t)(q + 2) * CHN);
        float4 c3 = *(const float4*)(Fp + (size_t)(q + 3) * CHN);
        #pragma unroll
        for (int j = 0; j < 4; ++j) {
            float4 cu = (j == 0) ? c0 : (j == 1) ? c1 : (j == 2) ? c2 : c3;
            float e0 = __expf(v.x * tanh_fast(h.x + cu.x));
            float e1 = __expf(v.y * tanh_fast(h.y + cu.y));
            float e2 = __expf(v.z * tanh_fast(h.z + cu.z));
            float e3 = __expf(v.w * tanh_fast(h.w + cu.w));
            s0 += e0; s1 += e1; s2 += e2; s3 += e3;
            a0 = fmaf(e0, cu.x, a0); a1 = fmaf(e1, cu.y, a1);
            a2 = fmaf(e2, cu.z, a2); a3 = fmaf(e3, cu.w, a3);
        }
    }
    sS[threadIdx.x] = make_float4(s0, s1, s2, s3);
    sW[threadIdx.x] = make_float4(a0, a1, a2, a3);
    __syncthreads();
    if (threadIdx.x < 64) {
        float4 S = sS[threadIdx.x];
        float4 W = sW[threadIdx.x];
        #pragma unroll
        for (int j = 1; j < 4; ++j) {
            float4 s = sS[j * 64 + threadIdx.x];
            float4 q = sW[j * 64 + threadIdx.x];
            S.x += s.x; S.y += s.y; S.z += s.z; S.w += s.w;
            W.x += q.x; W.y += q.y; W.z += q.z; W.w += q.w;
        }
        int base = (b * TS + ts) * CHN + threadIdx.x * 4;
        *(float4*)(pS + base) = S;
        *(float4*)(pW + base) = W;
    }
}

// ---------------- K4: reduce TS chunks -> c_t + Apk(c) -------------------------------
__global__ __launch_bounds__(256) void k4_combine(const float* __restrict__ pS,
    const float* __restrict__ pW, float* __restrict__ out_ct, u32* __restrict__ Apk) {
    __shared__ float sc[CHN];
    const int b = blockIdx.x;
    const int ch = threadIdx.x;
    float S = 0.0f, W = 0.0f;
    #pragma unroll
    for (int j = 0; j < TS; ++j) {
        int idx = (b * TS + j) * CHN + ch;
        S += pS[idx];
        W += pW[idx];
    }
    float c = W / S;
    out_ct[b * CHN + ch] = c;
    sc[ch] = c;
    __syncthreads();
    if (ch < 128)                      // packed pairs 64..191 (c part, k=128..383)
        Apk[apk_idx(64 + ch, b)] = pack_bf2(sc[2 * ch], sc[2 * ch + 1]);
}

// ---------------- K5: MFMA bf16 logits -> bf16 exp + per-block row partials ----------
// grid (250 v-tiles of 128, 2 b-halves) x 256 thr. Wave computes 32b x 32v, K=384
// via 24 x mfma_f32_32x32x16_bf16. W streamed f32 -> truncated bf16, 2-tile-deep
// prefetch (16 loads in flight).
__global__ __launch_bounds__(256) void k5_logits(const float* __restrict__ Wo,
    const float* __restrict__ Wct2, const u32* __restrict__ Apk,
    u16* __restrict__ expb, float* __restrict__ psum) {
    __shared__ float rp[4][32];
    const int t    = threadIdx.x;
    const int lane = t & 63;
    const int wv   = t >> 6;
    const int m    = lane & 31;        // local b (A row / C col)
    const int kq   = lane >> 5;        // k-half select
    const int y    = blockIdx.y;
    const int n0   = blockIdx.x * 128 + wv * 32;
    const int gb0  = y * 32;

    uint4 af[24];
    #pragma unroll
    for (int tt = 0; tt < 24; ++tt)
        af[tt] = *(const uint4*)&Apk[((size_t)((tt * 2 + kq) * 64) + gb0 + m) * 4];

    f32x16 acc = {0.0f, 0.0f, 0.0f, 0.0f, 0.0f, 0.0f, 0.0f, 0.0f,
                  0.0f, 0.0f, 0.0f, 0.0f, 0.0f, 0.0f, 0.0f, 0.0f};

    float wbuf[3][8];
    #pragma unroll
    for (int pf = 0; pf < 2; ++pf) {   // prefetch tiles 0,1 (rows < 40 -> always Wo)
        const float* c0 = Wo + (size_t)(pf * 16 + kq * 8) * VV + n0 + m;
        #pragma unroll
        for (int j = 0; j < 8; ++j) wbuf[pf][j] = c0[(size_t)j * VV];
    }

    #pragma unroll
    for (int tt = 0; tt < 24; ++tt) {
        if (tt < 22) {                 // prefetch tile tt+2
            const int kn = (tt + 2) * 16 + kq * 8;
            const float* cn = (kn < LL ? Wo + (size_t)kn * VV
                                       : Wct2 + (size_t)(kn - LL) * VV) + n0 + m;
            #pragma unroll
            for (int j = 0; j < 8; ++j) wbuf[(tt + 2) % 3][j] = cn[(size_t)j * VV];
        }
        short8 a, b;
        u32 ax = af[tt].x, ay = af[tt].y, az = af[tt].z, aw = af[tt].w;
        #pragma unroll
        for (int r = 0; r < 4; ++r) {
            u32 lo = __float_as_uint(wbuf[tt % 3][2 * r]);
            u32 hi = __float_as_uint(wbuf[tt % 3][2 * r + 1]);
            u32 bp = (lo >> 16) | (hi & 0xffff0000u);       // truncate-to-bf16 pair
            u32 ap = (r == 0) ? ax : (r == 1) ? ay : (r == 2) ? az : aw;
            a[2 * r]     = (short)(ap & 0xffff);
            a[2 * r + 1] = (short)(ap >> 16);
            b[2 * r]     = (short)(bp & 0xffff);
            b[2 * r + 1] = (short)(bp >> 16);
        }
        acc = __builtin_amdgcn_mfma_f32_32x32x16_bf16(a, b, acc, 0, 0, 0);
    }

    // epilogue: exp (f32), bf16 store, row partials. C/D: col=m, row=(r&3)+8(r>>2)+4kq
    float ex[16];
    #pragma unroll
    for (int r = 0; r < 16; ++r) {
        const int row = (r & 3) + 8 * (r >> 2) + 4 * kq;
        ex[r] = __expf(acc[r]);                             // logits bounded ~|4|
        expb[(size_t)(gb0 + row) * VV + n0 + m] = f2bf(ex[r]);
    }
    #pragma unroll
    for (int r = 0; r < 16; ++r) {                          // sum across 32 cols
        float s = ex[r];
        s += __shfl_xor(s, 1, 64);  s += __shfl_xor(s, 2, 64);
        s += __shfl_xor(s, 4, 64);  s += __shfl_xor(s, 8, 64);
        s += __shfl_xor(s, 16, 64);
        ex[r] = s;
    }
    if (m == 0) {                                           // lanes 0 and 32
        #pragma unroll
        for (int r = 0; r < 16; ++r)
            rp[wv][(r & 3) + 8 * (r >> 2) + 4 * kq] = ex[r];
    }
    __syncthreads();
    if (t < 32)
        psum[(size_t)blockIdx.x * BB + gb0 + t] =
            rp[0][t] + rp[1][t] + rp[2][t] + rp[3][t];
}

// ---------------- K5c: rowsum (in-block) + normalize bf16 exp -> f32 O ---------------
// grid (64 rows, 4 segs of 8000 v) x 256 thr.
__global__ __launch_bounds__(256) void k5c_norm(const u16* __restrict__ expb,
    const float* __restrict__ psum, float* __restrict__ O) {
    __shared__ float red[256];
    const int b   = blockIdx.x;
    const int seg = blockIdx.y;
    const int t   = threadIdx.x;

    red[t] = (t < NC1) ? psum[(size_t)t * BB + b] : 0.0f;
    __syncthreads();
    #pragma unroll
    for (int off = 128; off > 0; off >>= 1) {
        if (t < off) red[t] += red[t + off];
        __syncthreads();
    }
    const float inv = fast_rcp(red[0]);

    const u16* src = expb + (size_t)b * VV + seg * 8000;
    float* dst     = O + (size_t)b * VV + seg * 8000;
    #pragma unroll 2
    for (int i = t; i < 2000; i += 256) {            // 2000 x (4 bf16)
        uint2 pk = *(const uint2*)(src + i * 4);
        float4 f;
        f.x = bf2f((u16)(pk.x & 0xffff)) * inv;
        f.y = bf2f((u16)(pk.x >> 16)) * inv;
        f.z = bf2f((u16)(pk.y & 0xffff)) * inv;
        f.w = bf2f((u16)(pk.y >> 16)) * inv;
        *(float4*)(dst + i * 4) = f;
    }
}

extern "C" void kernel_launch(void* const* d_in, const int* in_sizes, int n_in,
                              void* d_out, int out_size, void* d_ws, size_t ws_size,
                              hipStream_t stream) {
    (void)in_sizes; (void)n_in; (void)out_size; (void)ws_size;
    const float* pcv       = (const float*)d_in[0];
    const float* F         = (const float*)d_in[1];
    const float* prev_char = (const float*)d_in[2];
    const float* state_h   = (const float*)d_in[3];
    const float* state_c   = (const float*)d_in[4];
    const float* Wc        = (const float*)d_in[5];
    const float* Wct1      = (const float*)d_in[6];
    const float* Wo        = (const float*)d_in[7];
    const float* Wct2      = (const float*)d_in[8];
    const float* lstm_k    = (const float*)d_in[9];
    const float* lstm_r    = (const float*)d_in[10];
    const float* W_h       = (const float*)d_in[11];
    const float* Vattn     = (const float*)d_in[12];

    // outputs: float32, concatenated flat in return order
    float* outO  = (float*)d_out;                  // [64][32000]
    float* outCt = outO + (size_t)BB * VV;         // [64][256]
    float* outH  = outCt + (size_t)BB * CHN;       // [64][128]
    float* outC  = outH + (size_t)BB * LL;         // [64][128]

    float* ws     = (float*)d_ws;
    float* part   = ws;                            // 250*64*64 = 1,024,000 f
    float* pS     = part + (size_t)NC1 * BB * EE;  // 64*16*256 = 262,144 f
    float* pW     = pS + (size_t)BB * TS * CHN;    // 262,144 f
    float* Htfm   = pW + (size_t)BB * TS * CHN;    // 16,384 f
    float* psum   = Htfm + (size_t)BB * CHN;       // 250*64 = 16,000 f
    u32*   Apk    = (u32*)(psum + (size_t)NC1 * BB);   // 24*2*64*4 = 12,288 u32
    u16*   expb   = (u16*)(Apk + 12288);           // 64*32000 u16 = 4.1 MB

    hipLaunchKernelGGL(k1_stage1, dim3(NC1, 2), dim3(256), 0, stream, prev_char, Wc, part);
    hipLaunchKernelGGL(k2_lstm, dim3(BB), dim3(512), 0, stream, part, pcv, state_h,
                       state_c, Wct1, lstm_k, lstm_r, W_h, outH, outC, Apk, Htfm);
    hipLaunchKernelGGL(k3_attn, dim3(BB, TS), dim3(256), 0, stream, F, Htfm, Vattn, pS, pW);
    hipLaunchKernelGGL(k4_combine, dim3(BB), dim3(256), 0, stream, pS, pW, outCt, Apk);
    hipLaunchKernelGGL(k5_logits, dim3(NC1, 2), dim3(256), 0, stream, Wo, Wct2, Apk, expb, psum);
    hipLaunchKernelGGL(k5c_norm, dim3(BB, 4), dim3(256), 0, stream, expb, psum, outO);
}